// Round 9
// baseline (1779.595 us; speedup 1.0000x reference)
//
#include <hip/hip_runtime.h>
#include <cstdint>

typedef __attribute__((ext_vector_type(4))) int i32x4;

#define XROWS  22
#define ROWB   2048              // LDS bytes per staged row (w 0..31, 64B each)
#define WSLICE 8192
#define WB_BYTES 409600          // wb (401408) rounded up
#define XT_BYTES ((size_t)16 * 112 * 128 * 64)
#define NTILES128 784            // co128 x 16x16 tiles
#define GRID_MAIN 768            // 3 blocks/CU x 256 CU; first 16 blocks dual

__device__ __forceinline__ void g2lds16(const void* g, void* l) {
  __builtin_amdgcn_global_load_lds(
      (const __attribute__((address_space(1))) unsigned int*)g,
      (__attribute__((address_space(3))) unsigned int*)l, 16, 0, 0);
}

// ---- standalone W pack (fallback path): wb[((s*4+g)*128+co)*16+lo], s=kh*7+kw
__global__ void prep_w(const float* __restrict__ w1,
                       const float* __restrict__ w2,
                       const float* __restrict__ w3,
                       signed char* __restrict__ wb) {
  int t = blockIdx.x * 256 + threadIdx.x;
  int lo = t & 15;
  int co = (t >> 4) & 127;
  int g  = (t >> 11) & 3;
  int s  = t >> 13;
  if (s >= 49) return;
  int kh = s / 7, kw = s % 7;
  int ci = g * 16 + lo;
  int base = ((co * 64 + ci) * 7 + kh) * 3;
  float v;
  if (kw < 3)       v = w1[base + kw];
  else if (kw == 3) v = w2[base + 1];
  else              v = w3[base + kw - 4];
  wb[t] = (signed char)(int)v;
}

// ---- merged prep: X pre-transpose + W pack.
// xt[n][h][w(128)][ci(64)] i8, clamped, 16B-granule-swizzled (granule p holds
// ci-granule p ^ ((w>>1)&3)).
__global__ void prep_xw(const int* __restrict__ x,
                        const float* __restrict__ w1,
                        const float* __restrict__ w2,
                        const float* __restrict__ w3,
                        signed char* __restrict__ xt,
                        signed char* __restrict__ wb) {
  __shared__ unsigned char T[64 * 68];
  const int tid = threadIdx.x;
  const int wt = blockIdx.x * 64, h = blockIdx.y, n = blockIdx.z;
  const int fid = (blockIdx.z * 112 + blockIdx.y) * 2 + blockIdx.x;

  if (fid < 1568) {                              // W pack: 1568*256 = 401408 elems
    int t = fid * 256 + tid;
    int lo = t & 15;
    int co = (t >> 4) & 127;
    int g  = (t >> 11) & 3;
    int s  = t >> 13;
    int kh = s / 7, kw = s % 7;
    int ci = g * 16 + lo;
    int base = ((co * 64 + ci) * 7 + kh) * 3;
    float v;
    if (kw < 3)       v = w1[base + kw];
    else if (kw == 3) v = w2[base + 1];
    else              v = w3[base + kw - 4];
    wb[t] = (signed char)(int)v;
  }

  {
    const int wr = tid & 63;
    const int cb = (tid >> 6) * 16;
    int ws = wt + wr; ws = ws < 112 ? ws : 111;
    const int* xp = x + (((size_t)n * 64 + cb) * 112 + h) * 112 + ws;
    #pragma unroll
    for (int g4 = 0; g4 < 4; ++g4) {
      uint32_t v = 0;
      #pragma unroll
      for (int j = 0; j < 4; ++j) {
        int a = xp[(g4 * 4 + j) * 12544];
        a = a < 0 ? 0 : (a > 7 ? 7 : a);
        v |= (uint32_t)a << (8 * j);
      }
      *(uint32_t*)&T[wr * 68 + cb + g4 * 4] = v;
    }
  }
  __syncthreads();
  {
    const int wo = tid >> 2, q = tid & 3;
    const int key = ((wt + wo) >> 1) & 3;
    const int sg = (q ^ key) << 4;
    int4 v;
    v.x = *(const int*)&T[wo * 68 + sg + 0];
    v.y = *(const int*)&T[wo * 68 + sg + 4];
    v.z = *(const int*)&T[wo * 68 + sg + 8];
    v.w = *(const int*)&T[wo * 68 + sg + 12];
    *(int4*)&xt[(((size_t)n * 112 + h) * 128 + wt + wo) * 64 + q * 16] = v;
  }
}

#define MFMA(acc, a, b) acc = __builtin_amdgcn_mfma_i32_16x16x64_i8(a, b, acc, 0, 0, 0)

// ---- main conv: co128 x 16x16 tile, 512 threads / 8 waves, wave = co16 x 16x16.
// Grid 768 (3 blocks/CU, 6 waves/SIMD); blocks 0..15 run a second tile.
__global__ __launch_bounds__(512, 6)
void conv7w(const signed char* __restrict__ xt,
            const signed char* __restrict__ wb,
            float* __restrict__ out) {
  __shared__ __align__(16) unsigned char Xs[XROWS * ROWB];   // 45056 B

  const int tid  = threadIdx.x;
  const int lane = tid & 63;
  const int wid  = tid >> 6;               // wave = co16 slice of co128 (0..7)
  const int lrow = lane & 15;
  const int lkg  = lane >> 4;

  // bijective XCD chunking: 768 = 8 * 96
  const int L  = blockIdx.x;
  const int Lp = (L & 7) * 96 + (L >> 3);
  const int npass = (L < 16) ? 2 : 1;

  for (int pass = 0; pass < npass; ++pass) {
    const int t = (pass == 0) ? Lp : (GRID_MAIN + L);   // tiles 768..783 on dual blocks
    const int bx = t % 7;
    const int t7 = t / 7;
    const int by = t7 % 7;
    const int n  = t7 / 7;
    const int ho_base = by * 16;
    const int wo_base = bx * 16;

    // A-frag base: wb addr = s*8192 + g*2048 + co*16 + lo; co = wid*16 + lrow
    const signed char* aB = wb + lkg * 2048 + (wid * 16 + lrow) * 16;

    i32x4 Aa = *(const i32x4*)aB;        // slice (kh=0, kw=0)
    i32x4 Ab;

    if (pass) __syncthreads();           // protect Xs reuse across passes

    for (int r = wid; r < XROWS; r += 8) {
      int h = ho_base + r; h = h < 112 ? h : 111;   // clamped rows feed only masked outputs
      const signed char* src = xt + (((size_t)n * 112 + h) * 128 + wo_base) * 64;
      g2lds16(src + lane * 16, &Xs[r * ROWB]);
      g2lds16(src + 1024 + lane * 16, &Xs[r * ROWB + 1024]);
    }
    asm volatile("s_waitcnt vmcnt(0)" ::: "memory");
    __syncthreads();

    i32x4 acc[16];
    #pragma unroll
    for (int j = 0; j < 16; ++j) acc[j] = (i32x4){0, 0, 0, 0};

    for (int kw = 0; kw < 7; ++kw) {
      const int w_l  = lrow + kw;
      const int bcol = w_l * 64 + ((lkg ^ ((w_l >> 1) & 3)) << 4);
      i32x4 B[16];                        // ring: slot r&15 holds row r
      #pragma unroll
      for (int b = 0; b < 16; ++b)
        B[b] = *(const i32x4*)&Xs[b * ROWB + bcol];

      #pragma unroll
      for (int kh = 0; kh < 7; ++kh) {
        // prefetch A for next slice: (kh+1,kw) or (0,kw+1); s = kh*7+kw
        const signed char* apn =
            aB + (size_t)(kh < 6 ? (kh + 1) * 7 + kw : (kw < 6 ? kw + 1 : 0)) * WSLICE;
        __builtin_amdgcn_s_setprio(1);
        if ((kh & 1) == 0) {
          Ab = *(const i32x4*)apn;
          #pragma unroll
          for (int j = 0; j < 16; ++j)
            MFMA(acc[j], Aa, B[(kh + j) & 15]);
        } else {
          Aa = *(const i32x4*)apn;
          #pragma unroll
          for (int j = 0; j < 16; ++j)
            MFMA(acc[j], Ab, B[(kh + j) & 15]);
        }
        __builtin_amdgcn_s_setprio(0);
        if (kh < 6)                       // row kh dead; bring row kh+16 into slot kh
          B[kh] = *(const i32x4*)&Xs[(kh + 16) * ROWB + bcol];
      }
      Aa = Ab;                            // kh=6 (even) loaded next-kw slice into Ab
    }

    // epilogue: C/D map col=lane&15 (wo), row=(lane>>4)*4+jj (co); i32->f32 exact
    const int wo = wo_base + lrow;
    if (wo < 106) {
      const int co = wid * 16 + lkg * 4;
      #pragma unroll
      for (int j = 0; j < 16; ++j) {
        const int ho = ho_base + j;
        if (ho < 106) {
          float* op = out + (((size_t)n * 128 + co) * 106 + ho) * 106 + wo;
          #pragma unroll
          for (int jj = 0; jj < 4; ++jj)
            op[(size_t)jj * 11236] = (float)acc[j][jj];
        }
      }
    }
  }
}

// ---- fallback (small ws): static grid 1568, stages straight from NCHW x
__global__ __launch_bounds__(256, 3)
void conv7f(const int* __restrict__ x,
            const signed char* __restrict__ wb, float* __restrict__ out) {
  __shared__ __align__(16) unsigned char Xs[XROWS * ROWB];

  const int tid  = threadIdx.x;
  const int lane = tid & 63;
  const int wid  = tid >> 6;
  const int lrow = lane & 15;
  const int lkg  = lane >> 4;

  const int L  = blockIdx.x;
  const int Lp = (L & 7) * 196 + (L >> 3);
  const int coh = Lp & 1;
  const int r2  = Lp >> 1;
  const int bx  = r2 % 7;
  const int t7  = r2 / 7;
  const int by  = t7 % 7;
  const int n   = t7 / 7;
  const int ho_base = by * 16;
  const int wo_base = bx * 16;

  const signed char* aB = wb + lkg * 2048 + coh * 1024 + lrow * 16;
  i32x4 A[4];
  #pragma unroll
  for (int m = 0; m < 4; ++m) A[m] = *(const i32x4*)(aB + m * 256);

  {
    const int w_a  = tid & 15,       cg_a  = tid >> 4;
    const int w_b2 = 16 + (tid & 7), cg_b2 = tid >> 3;
    const bool doB = (tid < 128) && ((tid & 7) < 6);
    const int keyA = ((w_a >> 1) & 3) << 2;
    const int keyB = ((w_b2 >> 1) & 3) << 2;
    for (int r = 0; r < XROWS; ++r) {
      int h = ho_base + r; h = h < 112 ? h : 111;
      const int* xr = x + (size_t)n * 64 * 12544 + h * 112;
      {
        int wc = wo_base + w_a; wc = wc < 112 ? wc : 111;
        uint32_t v = 0;
        #pragma unroll
        for (int j = 0; j < 4; ++j) {
          int a = xr[(cg_a * 4 + j) * 12544 + wc];
          a = a < 0 ? 0 : (a > 7 ? 7 : a);
          v |= (uint32_t)a << (8 * j);
        }
        *(uint32_t*)&Xs[r * ROWB + w_a * 64 + ((cg_a ^ keyA) << 2)] = v;
      }
      if (doB) {
        int wc = wo_base + w_b2; wc = wc < 112 ? wc : 111;
        uint32_t v = 0;
        #pragma unroll
        for (int j = 0; j < 4; ++j) {
          int a = xr[(cg_b2 * 4 + j) * 12544 + wc];
          a = a < 0 ? 0 : (a > 7 ? 7 : a);
          v |= (uint32_t)a << (8 * j);
        }
        *(uint32_t*)&Xs[r * ROWB + w_b2 * 64 + ((cg_b2 ^ keyB) << 2)] = v;
      }
    }
  }
  __syncthreads();

  i32x4 acc[4][4];
  #pragma unroll
  for (int m = 0; m < 4; ++m)
    #pragma unroll
    for (int b = 0; b < 4; ++b)
      acc[m][b] = (i32x4){0, 0, 0, 0};

  const int rowB = wid * 4;

  for (int kw = 0; kw < 7; ++kw) {
    const int w_l  = lrow + kw;
    const int bcol = w_l * 64 + ((lkg ^ ((w_l >> 1) & 3)) << 4);
    i32x4 B[8];
    #pragma unroll
    for (int b = 0; b < 4; ++b)
      B[b] = *(const i32x4*)&Xs[(rowB + b) * ROWB + bcol];
    #pragma unroll
    for (int kh = 0; kh < 7; ++kh) {
      if (kh < 6)
        B[(kh + 4) & 7] = *(const i32x4*)&Xs[(rowB + kh + 4) * ROWB + bcol];
      const signed char* apn = aB + (size_t)(kh < 6 ? (kh + 1) * 7 + kw : kw + 1) * WSLICE;
      #pragma unroll
      for (int m = 0; m < 4; ++m) {
        #pragma unroll
        for (int b = 0; b < 4; ++b)
          MFMA(acc[m][b], A[m], B[(kh + b) & 7]);
        A[m] = *(const i32x4*)(apn + m * 256);
      }
    }
  }

  const int wo = wo_base + lrow;
  if (wo < 106) {
    #pragma unroll
    for (int m = 0; m < 4; ++m) {
      const int co = coh * 64 + m * 16 + lkg * 4;
      #pragma unroll
      for (int b = 0; b < 4; ++b) {
        const int ho = ho_base + rowB + b;
        if (ho < 106) {
          float* op = out + (((size_t)n * 128 + co) * 106 + ho) * 106 + wo;
          #pragma unroll
          for (int j = 0; j < 4; ++j)
            op[(size_t)j * 11236] = (float)acc[m][b][j];
        }
      }
    }
  }
}

extern "C" void kernel_launch(void* const* d_in, const int* in_sizes, int n_in,
                              void* d_out, int out_size, void* d_ws, size_t ws_size,
                              hipStream_t stream) {
  const int*   x  = (const int*)d_in[0];
  const float* w1 = (const float*)d_in[1];
  const float* w2 = (const float*)d_in[2];
  const float* w3 = (const float*)d_in[3];
  float* outp = (float*)d_out;
  signed char* wbp = (signed char*)d_ws;
  signed char* xtp = wbp + WB_BYTES;

  if (ws_size >= WB_BYTES + XT_BYTES) {
    prep_xw<<<dim3(2, 112, 16), dim3(256), 0, stream>>>(x, w1, w2, w3, xtp, wbp);
    conv7w<<<dim3(GRID_MAIN), dim3(512), 0, stream>>>(xtp, wbp, outp);
  } else {
    prep_w<<<dim3(1568), dim3(256), 0, stream>>>(w1, w2, w3, wbp);
    conv7f<<<dim3(1568), dim3(256), 0, stream>>>(x, wbp, outp);
  }
}

// Round 10
// 108.313 us; speedup vs baseline: 16.4300x; 16.4300x over previous
//
#include <hip/hip_runtime.h>
#include <cstdint>

typedef __attribute__((ext_vector_type(4))) int i32x4;
typedef __attribute__((ext_vector_type(16))) int i32x16;

#define XROWS  22
#define ROWB   2048              // LDS bytes per staged row (w 0..31, 64B each)
#define WB_BYTES 409600          // wb (401408) rounded up
#define XT_BYTES ((size_t)16 * 112 * 128 * 64)
#define GRID_MAIN 1536           // 2 exact layers at 3 blocks/CU; first 32 blocks dual

__device__ __forceinline__ void g2lds16(const void* g, void* l) {
  __builtin_amdgcn_global_load_lds(
      (const __attribute__((address_space(1))) unsigned int*)g,
      (__attribute__((address_space(3))) unsigned int*)l, 16, 0, 0);
}

// ---- standalone W pack (fallback path, OLD 16x16 layout): pairs with conv7f
__global__ void prep_w(const float* __restrict__ w1,
                       const float* __restrict__ w2,
                       const float* __restrict__ w3,
                       signed char* __restrict__ wb) {
  int t = blockIdx.x * 256 + threadIdx.x;
  int lo = t & 15;
  int co = (t >> 4) & 127;
  int g  = (t >> 11) & 3;
  int s  = t >> 13;
  if (s >= 49) return;
  int kh = s / 7, kw = s % 7;
  int ci = g * 16 + lo;
  int base = ((co * 64 + ci) * 7 + kh) * 3;
  float v;
  if (kw < 3)       v = w1[base + kw];
  else if (kw == 3) v = w2[base + 1];
  else              v = w3[base + kw - 4];
  wb[t] = (signed char)(int)v;
}

// ---- merged prep: X pre-transpose + W pack (NEW 32x32 layout).
// xt[n][h][w(128)][ci(64)] i8, clamped, 16B-granule-swizzled (granule p holds
// ci-granule p ^ ((w>>1)&3)).
// wb2: addr = (((s*2 + k2)*2 + hk)*128 + co)*16 + b ; ci = k2*32 + hk*16 + b
__global__ void prep_xw(const int* __restrict__ x,
                        const float* __restrict__ w1,
                        const float* __restrict__ w2,
                        const float* __restrict__ w3,
                        signed char* __restrict__ xt,
                        signed char* __restrict__ wb) {
  __shared__ unsigned char T[64 * 68];
  const int tid = threadIdx.x;
  const int wt = blockIdx.x * 64, h = blockIdx.y, n = blockIdx.z;
  const int fid = (blockIdx.z * 112 + blockIdx.y) * 2 + blockIdx.x;

  if (fid < 1568) {                              // 1568*256 = 401408 elems
    int t = fid * 256 + tid;
    int b  = t & 15;
    int co = (t >> 4) & 127;
    int hk = (t >> 11) & 1;
    int k2 = (t >> 12) & 1;
    int s  = t >> 13;
    int kh = s / 7, kw = s % 7;
    int ci = k2 * 32 + hk * 16 + b;
    int base = ((co * 64 + ci) * 7 + kh) * 3;
    float v;
    if (kw < 3)       v = w1[base + kw];
    else if (kw == 3) v = w2[base + 1];
    else              v = w3[base + kw - 4];
    wb[t] = (signed char)(int)v;
  }

  {
    const int wr = tid & 63;
    const int cb = (tid >> 6) * 16;
    int ws = wt + wr; ws = ws < 112 ? ws : 111;
    const int* xp = x + (((size_t)n * 64 + cb) * 112 + h) * 112 + ws;
    #pragma unroll
    for (int g4 = 0; g4 < 4; ++g4) {
      uint32_t v = 0;
      #pragma unroll
      for (int j = 0; j < 4; ++j) {
        int a = xp[(g4 * 4 + j) * 12544];
        a = a < 0 ? 0 : (a > 7 ? 7 : a);
        v |= (uint32_t)a << (8 * j);
      }
      *(uint32_t*)&T[wr * 68 + cb + g4 * 4] = v;
    }
  }
  __syncthreads();
  {
    const int wo = tid >> 2, q = tid & 3;
    const int key = ((wt + wo) >> 1) & 3;
    const int sg = (q ^ key) << 4;
    int4 v;
    v.x = *(const int*)&T[wo * 68 + sg + 0];
    v.y = *(const int*)&T[wo * 68 + sg + 4];
    v.z = *(const int*)&T[wo * 68 + sg + 8];
    v.w = *(const int*)&T[wo * 68 + sg + 12];
    *(int4*)&xt[(((size_t)n * 112 + h) * 128 + wt + wo) * 64 + q * 16] = v;
  }
}

#define MFMA16(acc, a, b) acc = __builtin_amdgcn_mfma_i32_16x16x64_i8(a, b, acc, 0, 0, 0)
#define MFMA32(acc, a, b) acc = __builtin_amdgcn_mfma_i32_32x32x32_i8(a, b, acc, 0, 0, 0)

// ---- main conv: 32x32x32 i8 MFMA. Block co64 x 16ho x 16wo, 4 waves =
// [2 co32][2 ho8]. Wave: 4 acc-tiles (32co x (2ho x 16wo)), per slice 8 MFMA.
__global__ __launch_bounds__(256, 3)
void conv32(const signed char* __restrict__ xt,
            const signed char* __restrict__ wb,
            float* __restrict__ out) {
  __shared__ __align__(16) unsigned char Xs[XROWS * ROWB];   // 45056 B

  const int tid  = threadIdx.x;
  const int lane = tid & 63;
  const int wid  = tid >> 6;
  const int l15  = lane & 15;
  const int l4   = (lane >> 4) & 1;
  const int l5   = lane >> 5;
  const int cohalf = wid >> 1;             // co32 half within co64
  const int sph    = wid & 1;              // ho half (8 rows)
  const int spbase = sph * 8;

  // bijective XCD chunking: 1536 = 8 * 192
  const int L  = blockIdx.x;
  const int Lp = (L & 7) * 192 + (L >> 3);
  const int npass = (L < 32) ? 2 : 1;

  for (int pass = 0; pass < npass; ++pass) {
    const int t = (pass == 0) ? Lp : (GRID_MAIN + L);   // tiles 1536..1567 on dual blocks
    const int coh = t & 1;
    const int r2  = t >> 1;
    const int bx  = r2 % 7;
    const int t7  = r2 / 7;
    const int by  = t7 % 7;
    const int n   = t7 / 7;
    const int ho_base = by * 16;
    const int wo_base = bx * 16;

    // A: addr = (s*2+k2)*4096 + hk*2048 + co*16 ; co = coh*64 + cohalf*32 + (lane&31)
    const signed char* aB =
        wb + l5 * 2048 + (coh * 64 + cohalf * 32 + (lane & 31)) * 16;

    if (pass) __syncthreads();             // protect Xs reuse across passes

    for (int r = wid; r < XROWS; r += 4) {
      int h = ho_base + r; h = h < 112 ? h : 111;   // clamped rows feed only masked outputs
      const signed char* src = xt + (((size_t)n * 112 + h) * 128 + wo_base) * 64;
      g2lds16(src + lane * 16, &Xs[r * ROWB]);
      g2lds16(src + 1024 + lane * 16, &Xs[r * ROWB + 1024]);
    }
    asm volatile("s_waitcnt vmcnt(0)" ::: "memory");
    __syncthreads();

    i32x16 acc[4];
    #pragma unroll
    for (int tt = 0; tt < 4; ++tt)
      acc[tt] = (i32x16){0,0,0,0, 0,0,0,0, 0,0,0,0, 0,0,0,0};

    i32x4 Aa = *(const i32x4*)aB;          // slice (kh0,kw0,k2=0)
    i32x4 Ab;

    for (int kw = 0; kw < 7; ++kw) {
      const int w_l = l15 + kw;
      const int key = (w_l >> 1) & 3;
      // per-lane column base for each K-half; row part: spbase + lane-pair bit
      const int rbase = (spbase + l4) * ROWB + w_l * 64;
      const int cb0 = rbase + (((0 + l5) ^ key) << 4);
      const int cb1 = rbase + (((2 + l5) ^ key) << 4);
      #pragma unroll
      for (int k2 = 0; k2 < 2; ++k2) {
        const int cb = k2 ? cb1 : cb0;
        // frag(parity,p): rows spbase + 2p + parity + l4 ; ds offset (2p+parity)*ROWB
        i32x4 Be[4], Bo[4];
        #pragma unroll
        for (int p = 0; p < 4; ++p) {
          Be[p] = *(const i32x4*)&Xs[cb + (2 * p) * ROWB];
          Bo[p] = *(const i32x4*)&Xs[cb + (2 * p + 1) * ROWB];
        }
        #pragma unroll
        for (int kh = 0; kh < 7; ++kh) {
          // next-slice A pointer (kh+1, else k2+1, else kw+1; wraps harmlessly)
          const int nkh = (kh < 6) ? kh + 1 : 0;
          const int nk2 = (kh < 6) ? k2 : (k2 ^ 1);
          const int nkw = (kh < 6) ? kw : (k2 == 0 ? kw : (kw < 6 ? kw + 1 : 0));
          const signed char* apn = aB + (size_t)((nkh * 7 + nkw) * 2 + nk2) * 4096;
          __builtin_amdgcn_s_setprio(1);
          if ((kh & 1) == 0) {
            Ab = *(const i32x4*)apn;
            #pragma unroll
            for (int tt = 0; tt < 4; ++tt)
              MFMA32(acc[tt], Aa, Be[(tt + (kh >> 1)) & 3]);
          } else {
            Aa = *(const i32x4*)apn;
            #pragma unroll
            for (int tt = 0; tt < 4; ++tt)
              MFMA32(acc[tt], Ab, Bo[(tt + (kh >> 1)) & 3]);
          }
          __builtin_amdgcn_s_setprio(0);
          // ring refills (needed 2 kh later)
          if (kh == 0)      Be[0] = *(const i32x4*)&Xs[cb +  8 * ROWB];  // p4
          else if (kh == 1) Bo[0] = *(const i32x4*)&Xs[cb +  9 * ROWB];  // p4
          else if (kh == 2) Be[1] = *(const i32x4*)&Xs[cb + 10 * ROWB];  // p5
          else if (kh == 3) Bo[1] = *(const i32x4*)&Xs[cb + 11 * ROWB];  // p5
          else if (kh == 4) Be[2] = *(const i32x4*)&Xs[cb + 12 * ROWB];  // p6
        }
        Aa = Ab;                           // kh6 (even) loaded next pass's kh0 into Ab
      }
    }

    // epilogue: D col = lane&31 -> (ho-parity, wo); row = (j&3)+8*(j>>2)+4*l5 -> co
    const int wo = wo_base + l15;
    if (wo < 106) {
      #pragma unroll
      for (int tt = 0; tt < 4; ++tt) {
        const int ho = ho_base + spbase + 2 * tt + l4;
        if (ho < 106) {
          float* op = out +
              (((size_t)n * 128 + coh * 64 + cohalf * 32) * 106 + ho) * 106 + wo;
          #pragma unroll
          for (int j = 0; j < 16; ++j) {
            const int r = (j & 3) + 8 * (j >> 2) + 4 * l5;
            op[(size_t)r * 11236] = (float)acc[tt][j];
          }
        }
      }
    }
  }
}

// ---- fallback (small ws): static grid 1568, stages straight from NCHW x (16x16 MFMA)
__global__ __launch_bounds__(256, 3)
void conv7f(const int* __restrict__ x,
            const signed char* __restrict__ wb, float* __restrict__ out) {
  __shared__ __align__(16) unsigned char Xs[XROWS * ROWB];

  const int tid  = threadIdx.x;
  const int lane = tid & 63;
  const int wid  = tid >> 6;
  const int lrow = lane & 15;
  const int lkg  = lane >> 4;

  const int L  = blockIdx.x;
  const int Lp = (L & 7) * 196 + (L >> 3);
  const int coh = Lp & 1;
  const int r2  = Lp >> 1;
  const int bx  = r2 % 7;
  const int t7  = r2 / 7;
  const int by  = t7 % 7;
  const int n   = t7 / 7;
  const int ho_base = by * 16;
  const int wo_base = bx * 16;

  const signed char* aB = wb + lkg * 2048 + coh * 1024 + lrow * 16;
  i32x4 A[4];
  #pragma unroll
  for (int m = 0; m < 4; ++m) A[m] = *(const i32x4*)(aB + m * 256);

  {
    const int w_a  = tid & 15,       cg_a  = tid >> 4;
    const int w_b2 = 16 + (tid & 7), cg_b2 = tid >> 3;
    const bool doB = (tid < 128) && ((tid & 7) < 6);
    const int keyA = ((w_a >> 1) & 3) << 2;
    const int keyB = ((w_b2 >> 1) & 3) << 2;
    for (int r = 0; r < XROWS; ++r) {
      int h = ho_base + r; h = h < 112 ? h : 111;
      const int* xr = x + (size_t)n * 64 * 12544 + h * 112;
      {
        int wc = wo_base + w_a; wc = wc < 112 ? wc : 111;
        uint32_t v = 0;
        #pragma unroll
        for (int j = 0; j < 4; ++j) {
          int a = xr[(cg_a * 4 + j) * 12544 + wc];
          a = a < 0 ? 0 : (a > 7 ? 7 : a);
          v |= (uint32_t)a << (8 * j);
        }
        *(uint32_t*)&Xs[r * ROWB + w_a * 64 + ((cg_a ^ keyA) << 2)] = v;
      }
      if (doB) {
        int wc = wo_base + w_b2; wc = wc < 112 ? wc : 111;
        uint32_t v = 0;
        #pragma unroll
        for (int j = 0; j < 4; ++j) {
          int a = xr[(cg_b2 * 4 + j) * 12544 + wc];
          a = a < 0 ? 0 : (a > 7 ? 7 : a);
          v |= (uint32_t)a << (8 * j);
        }
        *(uint32_t*)&Xs[r * ROWB + w_b2 * 64 + ((cg_b2 ^ keyB) << 2)] = v;
      }
    }
  }
  __syncthreads();

  i32x4 acc[4][4];
  #pragma unroll
  for (int m = 0; m < 4; ++m)
    #pragma unroll
    for (int b = 0; b < 4; ++b)
      acc[m][b] = (i32x4){0, 0, 0, 0};

  const int rowB = wid * 4;

  for (int kw = 0; kw < 7; ++kw) {
    const int w_l  = lrow + kw;
    const int bcol = w_l * 64 + ((lkg ^ ((w_l >> 1) & 3)) << 4);
    i32x4 B[8];
    #pragma unroll
    for (int b = 0; b < 4; ++b)
      B[b] = *(const i32x4*)&Xs[(rowB + b) * ROWB + bcol];
    #pragma unroll
    for (int kh = 0; kh < 7; ++kh) {
      if (kh < 6)
        B[(kh + 4) & 7] = *(const i32x4*)&Xs[(rowB + kh + 4) * ROWB + bcol];
      const signed char* apn = aB + (size_t)(kh < 6 ? (kh + 1) * 7 + kw : kw + 1) * 8192;
      #pragma unroll
      for (int m = 0; m < 4; ++m) {
        #pragma unroll
        for (int b = 0; b < 4; ++b)
          MFMA16(acc[m][b], A[m], B[(kh + b) & 7]);
        A[m] = *(const i32x4*)(apn + m * 256);
      }
    }
  }

  const int wo = wo_base + lrow;
  if (wo < 106) {
    #pragma unroll
    for (int m = 0; m < 4; ++m) {
      const int co = coh * 64 + m * 16 + lkg * 4;
      #pragma unroll
      for (int b = 0; b < 4; ++b) {
        const int ho = ho_base + rowB + b;
        if (ho < 106) {
          float* op = out + (((size_t)n * 128 + co) * 106 + ho) * 106 + wo;
          #pragma unroll
          for (int j = 0; j < 4; ++j)
            op[(size_t)j * 11236] = (float)acc[m][b][j];
        }
      }
    }
  }
}

extern "C" void kernel_launch(void* const* d_in, const int* in_sizes, int n_in,
                              void* d_out, int out_size, void* d_ws, size_t ws_size,
                              hipStream_t stream) {
  const int*   x  = (const int*)d_in[0];
  const float* w1 = (const float*)d_in[1];
  const float* w2 = (const float*)d_in[2];
  const float* w3 = (const float*)d_in[3];
  float* outp = (float*)d_out;
  signed char* wbp = (signed char*)d_ws;
  signed char* xtp = wbp + WB_BYTES;

  if (ws_size >= WB_BYTES + XT_BYTES) {
    prep_xw<<<dim3(2, 112, 16), dim3(256), 0, stream>>>(x, w1, w2, w3, xtp, wbp);
    conv32<<<dim3(GRID_MAIN), dim3(256), 0, stream>>>(xtp, wbp, outp);
  } else {
    prep_w<<<dim3(1568), dim3(256), 0, stream>>>(w1, w2, w3, wbp);
    conv7f<<<dim3(1568), dim3(256), 0, stream>>>(x, wbp, outp);
  }
}

// Round 11
// 68.657 us; speedup vs baseline: 25.9201x; 1.5776x over previous
//
#include <hip/hip_runtime.h>
#include <cstdint>

typedef __attribute__((ext_vector_type(4))) int i32x4;

#define XROWS  22
#define ROWB   2048              // LDS bytes per staged row (w 0..31, 64B each)
#define WSLICE 8192
#define WB_BYTES 409600          // wb (401408) rounded up
#define XT_BYTES ((size_t)16 * 112 * 128 * 64)
#define GRID_MAIN 1536           // 2 exact layers at 3 blocks/CU; first 32 blocks dual

__device__ __forceinline__ void g2lds16(const void* g, void* l) {
  __builtin_amdgcn_global_load_lds(
      (const __attribute__((address_space(1))) unsigned int*)g,
      (__attribute__((address_space(3))) unsigned int*)l, 16, 0, 0);
}

// ---- standalone W pack (fallback path): wb[((s*4+g)*128+co)*16+lo], s=kh*7+kw
__global__ void prep_w(const float* __restrict__ w1,
                       const float* __restrict__ w2,
                       const float* __restrict__ w3,
                       signed char* __restrict__ wb) {
  int t = blockIdx.x * 256 + threadIdx.x;
  int lo = t & 15;
  int co = (t >> 4) & 127;
  int g  = (t >> 11) & 3;
  int s  = t >> 13;
  if (s >= 49) return;
  int kh = s / 7, kw = s % 7;
  int ci = g * 16 + lo;
  int base = ((co * 64 + ci) * 7 + kh) * 3;
  float v;
  if (kw < 3)       v = w1[base + kw];
  else if (kw == 3) v = w2[base + 1];
  else              v = w3[base + kw - 4];
  wb[t] = (signed char)(int)v;
}

// ---- merged prep: X pre-transpose + W pack (16x16 layout, same as fallback).
// xt[n][h][w(128)][ci(64)] i8, clamped, 16B-granule-swizzled (granule p holds
// ci-granule p ^ ((w>>1)&3)).
__global__ void prep_xw(const int* __restrict__ x,
                        const float* __restrict__ w1,
                        const float* __restrict__ w2,
                        const float* __restrict__ w3,
                        signed char* __restrict__ xt,
                        signed char* __restrict__ wb) {
  __shared__ unsigned char T[64 * 68];
  const int tid = threadIdx.x;
  const int wt = blockIdx.x * 64, h = blockIdx.y, n = blockIdx.z;
  const int fid = (blockIdx.z * 112 + blockIdx.y) * 2 + blockIdx.x;

  if (fid < 1568) {                              // W pack: 1568*256 = 401408 elems
    int t = fid * 256 + tid;
    int lo = t & 15;
    int co = (t >> 4) & 127;
    int g  = (t >> 11) & 3;
    int s  = t >> 13;
    int kh = s / 7, kw = s % 7;
    int ci = g * 16 + lo;
    int base = ((co * 64 + ci) * 7 + kh) * 3;
    float v;
    if (kw < 3)       v = w1[base + kw];
    else if (kw == 3) v = w2[base + 1];
    else              v = w3[base + kw - 4];
    wb[t] = (signed char)(int)v;
  }

  {
    const int wr = tid & 63;
    const int cb = (tid >> 6) * 16;
    int ws = wt + wr; ws = ws < 112 ? ws : 111;
    const int* xp = x + (((size_t)n * 64 + cb) * 112 + h) * 112 + ws;
    #pragma unroll
    for (int g4 = 0; g4 < 4; ++g4) {
      uint32_t v = 0;
      #pragma unroll
      for (int j = 0; j < 4; ++j) {
        int a = xp[(g4 * 4 + j) * 12544];
        a = a < 0 ? 0 : (a > 7 ? 7 : a);
        v |= (uint32_t)a << (8 * j);
      }
      *(uint32_t*)&T[wr * 68 + cb + g4 * 4] = v;
    }
  }
  __syncthreads();
  {
    const int wo = tid >> 2, q = tid & 3;
    const int key = ((wt + wo) >> 1) & 3;
    const int sg = (q ^ key) << 4;
    int4 v;
    v.x = *(const int*)&T[wo * 68 + sg + 0];
    v.y = *(const int*)&T[wo * 68 + sg + 4];
    v.z = *(const int*)&T[wo * 68 + sg + 8];
    v.w = *(const int*)&T[wo * 68 + sg + 12];
    *(int4*)&xt[(((size_t)n * 112 + h) * 128 + wt + wo) * 64 + q * 16] = v;
  }
}

#define MFMA16(acc, a, b) acc = __builtin_amdgcn_mfma_i32_16x16x64_i8(a, b, acc, 0, 0, 0)

// One kw column: 16 B-ring reads, 7 kh batches of 16 MFMA.
// A-ring slot for (kw,kh) is (kh+PHASE)%3 with PHASE = kw%3 (compile-time).
// After batch kh retires its A, load slice +3 (consumption order c = kw*7+kh).
template<int PHASE>
__device__ __forceinline__ void kw_body(const int kw,
    const signed char* __restrict__ aB, const unsigned char* Xs,
    const int lrow, const int lkg,
    i32x4& A0, i32x4& A1, i32x4& A2, i32x4 (&acc)[16]) {
  const int w_l  = lrow + kw;
  const int bcol = w_l * 64 + ((lkg ^ ((w_l >> 1) & 3)) << 4);
  i32x4 B[16];                             // ring: slot r&15 holds row r
  #pragma unroll
  for (int b = 0; b < 16; ++b)
    B[b] = *(const i32x4*)&Xs[b * ROWB + bcol];

  #pragma unroll
  for (int kh = 0; kh < 7; ++kh) {
    // next+3 slice in consumption order: (kh+3,kw) or (kh-4,kw+1); wb s = kh*7+kw
    const int nkh = (kh <= 3) ? kh + 3 : kh - 4;
    const int nkw = (kh <= 3) ? kw : kw + 1;        // kw+1==7 reads valid garbage (unused)
    const signed char* apn = aB + (size_t)(nkh * 7 + nkw) * WSLICE;
    __builtin_amdgcn_s_setprio(1);
    if (((kh + PHASE) % 3) == 0) {
      MFMA16(acc[0], A0, B[kh]);                    // j=0: last consumer of slot kh
      if (kh < 6) B[kh] = *(const i32x4*)&Xs[(kh + 16) * ROWB + bcol];  // early refill
      #pragma unroll
      for (int j = 1; j < 16; ++j) MFMA16(acc[j], A0, B[(kh + j) & 15]);
      __builtin_amdgcn_s_setprio(0);
      A0 = *(const i32x4*)apn;                      // reload freed slot (slice +3)
    } else if (((kh + PHASE) % 3) == 1) {
      MFMA16(acc[0], A1, B[kh]);
      if (kh < 6) B[kh] = *(const i32x4*)&Xs[(kh + 16) * ROWB + bcol];
      #pragma unroll
      for (int j = 1; j < 16; ++j) MFMA16(acc[j], A1, B[(kh + j) & 15]);
      __builtin_amdgcn_s_setprio(0);
      A1 = *(const i32x4*)apn;
    } else {
      MFMA16(acc[0], A2, B[kh]);
      if (kh < 6) B[kh] = *(const i32x4*)&Xs[(kh + 16) * ROWB + bcol];
      #pragma unroll
      for (int j = 1; j < 16; ++j) MFMA16(acc[j], A2, B[(kh + j) & 15]);
      __builtin_amdgcn_s_setprio(0);
      A2 = *(const i32x4*)apn;
    }
  }
}

// ---- main conv: static grid 1536 (+32 dual blocks). Wave = co16 x ho16 x wo16:
// 1 A-load + 16 MFMA per slice, B 16-deep ring, A 3-deep ring.
__global__ __launch_bounds__(256, 3)
void conv7s(const signed char* __restrict__ xt,
            const signed char* __restrict__ wb,
            float* __restrict__ out) {
  __shared__ __align__(16) unsigned char Xs[XROWS * ROWB];   // 45056 B

  const int tid  = threadIdx.x;
  const int lane = tid & 63;
  const int wid  = tid >> 6;               // wave = co16 quarter of co64
  const int lrow = lane & 15;
  const int lkg  = lane >> 4;

  // bijective XCD chunking: 1536 = 8 * 192
  const int L  = blockIdx.x;
  const int Lp = (L & 7) * 192 + (L >> 3);
  const int npass = (L < 32) ? 2 : 1;

  for (int pass = 0; pass < npass; ++pass) {
    const int t = (pass == 0) ? Lp : (GRID_MAIN + L);   // tiles 1536..1567 on dual blocks
    const int coh = t & 1;
    const int r2  = t >> 1;
    const int bx  = r2 % 7;
    const int t7  = r2 / 7;
    const int by  = t7 % 7;
    const int n   = t7 / 7;
    const int ho_base = by * 16;
    const int wo_base = bx * 16;

    // A-frag base: wb addr = s*8192 + g*2048 + co*16; co = coh*64 + wid*16 + lrow
    const signed char* aB = wb + lkg * 2048 + (coh * 64 + wid * 16 + lrow) * 16;

    // A-ring prologue: slices (kh,kw) = (0,0),(1,0),(2,0) -> slots 0,1,2 (in flight)
    i32x4 A0 = *(const i32x4*)(aB);
    i32x4 A1 = *(const i32x4*)(aB + 7 * WSLICE);
    i32x4 A2 = *(const i32x4*)(aB + 14 * WSLICE);

    if (pass) __syncthreads();             // protect Xs reuse across passes

    for (int r = wid; r < XROWS; r += 4) {
      int h = ho_base + r; h = h < 112 ? h : 111;   // clamped rows feed only masked outputs
      const signed char* src = xt + (((size_t)n * 112 + h) * 128 + wo_base) * 64;
      g2lds16(src + lane * 16, &Xs[r * ROWB]);
      g2lds16(src + 1024 + lane * 16, &Xs[r * ROWB + 1024]);
    }
    asm volatile("s_waitcnt vmcnt(0)" ::: "memory");
    __syncthreads();

    i32x4 acc[16];
    #pragma unroll
    for (int j = 0; j < 16; ++j) acc[j] = (i32x4){0, 0, 0, 0};

    for (int kwb = 0; kwb < 6; kwb += 3) { // PHASE = kw % 3, compile-time per body
      kw_body<0>(kwb + 0, aB, Xs, lrow, lkg, A0, A1, A2, acc);
      kw_body<1>(kwb + 1, aB, Xs, lrow, lkg, A0, A1, A2, acc);
      kw_body<2>(kwb + 2, aB, Xs, lrow, lkg, A0, A1, A2, acc);
    }
    kw_body<0>(6, aB, Xs, lrow, lkg, A0, A1, A2, acc);

    // epilogue: C/D map col=lane&15 (wo), row=(lane>>4)*4+jj (co); i32->f32 exact
    const int wo = wo_base + lrow;
    if (wo < 106) {
      const int co = coh * 64 + wid * 16 + lkg * 4;
      #pragma unroll
      for (int j = 0; j < 16; ++j) {
        const int ho = ho_base + j;
        if (ho < 106) {
          float* op = out + (((size_t)n * 128 + co) * 106 + ho) * 106 + wo;
          #pragma unroll
          for (int jj = 0; jj < 4; ++jj)
            op[(size_t)jj * 11236] = (float)acc[j][jj];
        }
      }
    }
  }
}

// ---- fallback (small ws): static grid 1568, stages straight from NCHW x
__global__ __launch_bounds__(256, 3)
void conv7f(const int* __restrict__ x,
            const signed char* __restrict__ wb, float* __restrict__ out) {
  __shared__ __align__(16) unsigned char Xs[XROWS * ROWB];

  const int tid  = threadIdx.x;
  const int lane = tid & 63;
  const int wid  = tid >> 6;
  const int lrow = lane & 15;
  const int lkg  = lane >> 4;

  const int L  = blockIdx.x;
  const int Lp = (L & 7) * 196 + (L >> 3);
  const int coh = Lp & 1;
  const int r2  = Lp >> 1;
  const int bx  = r2 % 7;
  const int t7  = r2 / 7;
  const int by  = t7 % 7;
  const int n   = t7 / 7;
  const int ho_base = by * 16;
  const int wo_base = bx * 16;

  const signed char* aB = wb + lkg * 2048 + coh * 1024 + lrow * 16;
  i32x4 A[4];
  #pragma unroll
  for (int m = 0; m < 4; ++m) A[m] = *(const i32x4*)(aB + m * 256);

  {
    const int w_a  = tid & 15,       cg_a  = tid >> 4;
    const int w_b2 = 16 + (tid & 7), cg_b2 = tid >> 3;
    const bool doB = (tid < 128) && ((tid & 7) < 6);
    const int keyA = ((w_a >> 1) & 3) << 2;
    const int keyB = ((w_b2 >> 1) & 3) << 2;
    for (int r = 0; r < XROWS; ++r) {
      int h = ho_base + r; h = h < 112 ? h : 111;
      const int* xr = x + (size_t)n * 64 * 12544 + h * 112;
      {
        int wc = wo_base + w_a; wc = wc < 112 ? wc : 111;
        uint32_t v = 0;
        #pragma unroll
        for (int j = 0; j < 4; ++j) {
          int a = xr[(cg_a * 4 + j) * 12544 + wc];
          a = a < 0 ? 0 : (a > 7 ? 7 : a);
          v |= (uint32_t)a << (8 * j);
        }
        *(uint32_t*)&Xs[r * ROWB + w_a * 64 + ((cg_a ^ keyA) << 2)] = v;
      }
      if (doB) {
        int wc = wo_base + w_b2; wc = wc < 112 ? wc : 111;
        uint32_t v = 0;
        #pragma unroll
        for (int j = 0; j < 4; ++j) {
          int a = xr[(cg_b2 * 4 + j) * 12544 + wc];
          a = a < 0 ? 0 : (a > 7 ? 7 : a);
          v |= (uint32_t)a << (8 * j);
        }
        *(uint32_t*)&Xs[r * ROWB + w_b2 * 64 + ((cg_b2 ^ keyB) << 2)] = v;
      }
    }
  }
  __syncthreads();

  i32x4 acc[4][4];
  #pragma unroll
  for (int m = 0; m < 4; ++m)
    #pragma unroll
    for (int b = 0; b < 4; ++b)
      acc[m][b] = (i32x4){0, 0, 0, 0};

  const int rowB = wid * 4;

  for (int kw = 0; kw < 7; ++kw) {
    const int w_l  = lrow + kw;
    const int bcol = w_l * 64 + ((lkg ^ ((w_l >> 1) & 3)) << 4);
    i32x4 B[8];
    #pragma unroll
    for (int b = 0; b < 4; ++b)
      B[b] = *(const i32x4*)&Xs[(rowB + b) * ROWB + bcol];
    #pragma unroll
    for (int kh = 0; kh < 7; ++kh) {
      if (kh < 6)
        B[(kh + 4) & 7] = *(const i32x4*)&Xs[(rowB + kh + 4) * ROWB + bcol];
      const signed char* apn = aB + (size_t)(kh < 6 ? (kh + 1) * 7 + kw : kw + 1) * WSLICE;
      #pragma unroll
      for (int m = 0; m < 4; ++m) {
        #pragma unroll
        for (int b = 0; b < 4; ++b)
          MFMA16(acc[m][b], A[m], B[(kh + b) & 7]);
        A[m] = *(const i32x4*)(apn + m * 256);
      }
    }
  }

  const int wo = wo_base + lrow;
  if (wo < 106) {
    #pragma unroll
    for (int m = 0; m < 4; ++m) {
      const int co = coh * 64 + m * 16 + lkg * 4;
      #pragma unroll
      for (int b = 0; b < 4; ++b) {
        const int ho = ho_base + rowB + b;
        if (ho < 106) {
          float* op = out + (((size_t)n * 128 + co) * 106 + ho) * 106 + wo;
          #pragma unroll
          for (int j = 0; j < 4; ++j)
            op[(size_t)j * 11236] = (float)acc[m][b][j];
        }
      }
    }
  }
}

extern "C" void kernel_launch(void* const* d_in, const int* in_sizes, int n_in,
                              void* d_out, int out_size, void* d_ws, size_t ws_size,
                              hipStream_t stream) {
  const int*   x  = (const int*)d_in[0];
  const float* w1 = (const float*)d_in[1];
  const float* w2 = (const float*)d_in[2];
  const float* w3 = (const float*)d_in[3];
  float* outp = (float*)d_out;
  signed char* wbp = (signed char*)d_ws;
  signed char* xtp = wbp + WB_BYTES;

  if (ws_size >= WB_BYTES + XT_BYTES) {
    prep_xw<<<dim3(2, 112, 16), dim3(256), 0, stream>>>(x, w1, w2, w3, xtp, wbp);
    conv7s<<<dim3(GRID_MAIN), dim3(256), 0, stream>>>(xtp, wbp, outp);
  } else {
    prep_w<<<dim3(1568), dim3(256), 0, stream>>>(w1, w2, w3, wbp);
    conv7f<<<dim3(1568), dim3(256), 0, stream>>>(x, wbp, outp);
  }
}

// Round 13
// 68.485 us; speedup vs baseline: 25.9852x; 1.0025x over previous
//
#include <hip/hip_runtime.h>
#include <cstdint>

typedef __attribute__((ext_vector_type(4))) int i32x4;

#define XROWS  22
#define ROWB   2048              // LDS bytes per staged row (w 0..31, 64B each)
#define WSLICE 8192
#define WB_BYTES 409600          // wb (401408) rounded up
#define XT_BYTES ((size_t)16 * 112 * 128 * 64)
#define GRID_MAIN 1536           // 2 exact layers at 3 blocks/CU; first 32 blocks dual

__device__ __forceinline__ void g2lds16(const void* g, void* l) {
  __builtin_amdgcn_global_load_lds(
      (const __attribute__((address_space(1))) unsigned int*)g,
      (__attribute__((address_space(3))) unsigned int*)l, 16, 0, 0);
}

// ---- standalone W pack (fallback path): wb[((s*4+g)*128+co)*16+lo], s=kh*7+kw
__global__ void prep_w(const float* __restrict__ w1,
                       const float* __restrict__ w2,
                       const float* __restrict__ w3,
                       signed char* __restrict__ wb) {
  int t = blockIdx.x * 256 + threadIdx.x;
  int lo = t & 15;
  int co = (t >> 4) & 127;
  int g  = (t >> 11) & 3;
  int s  = t >> 13;
  if (s >= 49) return;
  int kh = s / 7, kw = s % 7;
  int ci = g * 16 + lo;
  int base = ((co * 64 + ci) * 7 + kh) * 3;
  float v;
  if (kw < 3)       v = w1[base + kw];
  else if (kw == 3) v = w2[base + 1];
  else              v = w3[base + kw - 4];
  wb[t] = (signed char)(int)v;
}

// ---- merged prep: X pre-transpose + W pack (16x16 layout, same as fallback).
// xt[n][h][w(128)][ci(64)] i8, clamped, 16B-granule-swizzled (granule p holds
// ci-granule p ^ ((w>>1)&3)).
__global__ void prep_xw(const int* __restrict__ x,
                        const float* __restrict__ w1,
                        const float* __restrict__ w2,
                        const float* __restrict__ w3,
                        signed char* __restrict__ xt,
                        signed char* __restrict__ wb) {
  __shared__ unsigned char T[64 * 68];
  const int tid = threadIdx.x;
  const int wt = blockIdx.x * 64, h = blockIdx.y, n = blockIdx.z;
  const int fid = (blockIdx.z * 112 + blockIdx.y) * 2 + blockIdx.x;

  if (fid < 1568) {                              // W pack: 1568*256 = 401408 elems
    int t = fid * 256 + tid;
    int lo = t & 15;
    int co = (t >> 4) & 127;
    int g  = (t >> 11) & 3;
    int s  = t >> 13;
    int kh = s / 7, kw = s % 7;
    int ci = g * 16 + lo;
    int base = ((co * 64 + ci) * 7 + kh) * 3;
    float v;
    if (kw < 3)       v = w1[base + kw];
    else if (kw == 3) v = w2[base + 1];
    else              v = w3[base + kw - 4];
    wb[t] = (signed char)(int)v;
  }

  {
    const int wr = tid & 63;
    const int cb = (tid >> 6) * 16;
    int ws = wt + wr; ws = ws < 112 ? ws : 111;
    const int* xp = x + (((size_t)n * 64 + cb) * 112 + h) * 112 + ws;
    #pragma unroll
    for (int g4 = 0; g4 < 4; ++g4) {
      uint32_t v = 0;
      #pragma unroll
      for (int j = 0; j < 4; ++j) {
        int a = xp[(g4 * 4 + j) * 12544];
        a = a < 0 ? 0 : (a > 7 ? 7 : a);
        v |= (uint32_t)a << (8 * j);
      }
      *(uint32_t*)&T[wr * 68 + cb + g4 * 4] = v;
    }
  }
  __syncthreads();
  {
    const int wo = tid >> 2, q = tid & 3;
    const int key = ((wt + wo) >> 1) & 3;
    const int sg = (q ^ key) << 4;
    int4 v;
    v.x = *(const int*)&T[wo * 68 + sg + 0];
    v.y = *(const int*)&T[wo * 68 + sg + 4];
    v.z = *(const int*)&T[wo * 68 + sg + 8];
    v.w = *(const int*)&T[wo * 68 + sg + 12];
    *(int4*)&xt[(((size_t)n * 112 + h) * 128 + wt + wo) * 64 + q * 16] = v;
  }
}

#define MFMA16(acc, a, b) acc = __builtin_amdgcn_mfma_i32_16x16x64_i8(a, b, acc, 0, 0, 0)

// One kw column: 16 B-ring reads, 7 kh batches of 16 MFMA.
// Consumption order c = i*7 + kh where i = position in the (rotated) kw sequence.
// A-ring slot = (kh + PHASE) % 3, PHASE = i % 3 (compile-time).
// After batch kh retires its A, load slice c+3; next column is (kw+1)%7.
template<int PHASE>
__device__ __forceinline__ void kw_body(const int kw,
    const signed char* __restrict__ aB, const unsigned char* Xs,
    const int lrow, const int lkg,
    i32x4& A0, i32x4& A1, i32x4& A2, i32x4 (&acc)[16]) {
  const int w_l  = lrow + kw;
  const int bcol = w_l * 64 + ((lkg ^ ((w_l >> 1) & 3)) << 4);
  i32x4 B[16];                             // ring: slot r&15 holds row r
  #pragma unroll
  for (int b = 0; b < 16; ++b)
    B[b] = *(const i32x4*)&Xs[b * ROWB + bcol];

  #pragma unroll
  for (int kh = 0; kh < 7; ++kh) {
    // c+3 in rotated consumption order: (kh+3, kw) or (kh-4, (kw+1)%7); s = kh*7+kw
    const int nkh = (kh <= 3) ? kh + 3 : kh - 4;
    const int nkw = (kh <= 3) ? kw : (kw == 6 ? 0 : kw + 1);
    const signed char* apn = aB + (size_t)(nkh * 7 + nkw) * WSLICE;
    __builtin_amdgcn_s_setprio(1);
    if (((kh + PHASE) % 3) == 0) {
      MFMA16(acc[0], A0, B[kh]);                    // j=0: last consumer of slot kh
      if (kh < 6) B[kh] = *(const i32x4*)&Xs[(kh + 16) * ROWB + bcol];  // early refill
      #pragma unroll
      for (int j = 1; j < 16; ++j) MFMA16(acc[j], A0, B[(kh + j) & 15]);
      __builtin_amdgcn_s_setprio(0);
      A0 = *(const i32x4*)apn;                      // reload freed slot (slice c+3)
    } else if (((kh + PHASE) % 3) == 1) {
      MFMA16(acc[0], A1, B[kh]);
      if (kh < 6) B[kh] = *(const i32x4*)&Xs[(kh + 16) * ROWB + bcol];
      #pragma unroll
      for (int j = 1; j < 16; ++j) MFMA16(acc[j], A1, B[(kh + j) & 15]);
      __builtin_amdgcn_s_setprio(0);
      A1 = *(const i32x4*)apn;
    } else {
      MFMA16(acc[0], A2, B[kh]);
      if (kh < 6) B[kh] = *(const i32x4*)&Xs[(kh + 16) * ROWB + bcol];
      #pragma unroll
      for (int j = 1; j < 16; ++j) MFMA16(acc[j], A2, B[(kh + j) & 15]);
      __builtin_amdgcn_s_setprio(0);
      A2 = *(const i32x4*)apn;
    }
  }
}

// ---- main conv: static grid 1536 (+32 dual blocks). Wave = co16 x ho16 x wo16:
// 1 A-load + 16 MFMA per slice, B 16-deep ring, A 3-deep ring.
// Per-block kw rotation (start = (L>>3)%7) desynchronizes co-resident waves'
// non-MFMA phases (anti-convoy); integer accumulation makes any order exact.
__global__ __launch_bounds__(256, 3)
void conv7s(const signed char* __restrict__ xt,
            const signed char* __restrict__ wb,
            float* __restrict__ out) {
  __shared__ __align__(16) unsigned char Xs[XROWS * ROWB];   // 45056 B

  const int tid  = threadIdx.x;
  const int lane = tid & 63;
  const int wid  = tid >> 6;               // wave = co16 quarter of co64
  const int lrow = lane & 15;
  const int lkg  = lane >> 4;

  // bijective XCD chunking: 1536 = 8 * 192
  const int L  = blockIdx.x;
  const int Lp = (L & 7) * 192 + (L >> 3);
  const int npass = (L < 32) ? 2 : 1;

  // rotated kw sequence k0..k6 = start, start+1, ... (mod 7)
  const int k0 = (L >> 3) % 7;
  const int k1 = (k0 + 1) % 7;
  const int k2 = (k0 + 2) % 7;
  const int k3 = (k0 + 3) % 7;
  const int k4 = (k0 + 4) % 7;
  const int k5 = (k0 + 5) % 7;
  const int k6 = (k0 + 6) % 7;

  for (int pass = 0; pass < npass; ++pass) {
    const int t = (pass == 0) ? Lp : (GRID_MAIN + L);   // tiles 1536..1567 on dual blocks
    const int coh = t & 1;
    const int r2  = t >> 1;
    const int bx  = r2 % 7;
    const int t7  = r2 / 7;
    const int by  = t7 % 7;
    const int n   = t7 / 7;
    const int ho_base = by * 16;
    const int wo_base = bx * 16;

    // A-frag base: wb addr = s*8192 + g*2048 + co*16; co = coh*64 + wid*16 + lrow
    const signed char* aB = wb + lkg * 2048 + (coh * 64 + wid * 16 + lrow) * 16;

    // A-ring prologue: slices (kh,kw) = (0,k0),(1,k0),(2,k0) -> slots 0,1,2
    i32x4 A0 = *(const i32x4*)(aB + (size_t)(0 * 7 + k0) * WSLICE);
    i32x4 A1 = *(const i32x4*)(aB + (size_t)(1 * 7 + k0) * WSLICE);
    i32x4 A2 = *(const i32x4*)(aB + (size_t)(2 * 7 + k0) * WSLICE);

    if (pass) __syncthreads();             // protect Xs reuse across passes

    for (int r = wid; r < XROWS; r += 4) {
      int h = ho_base + r; h = h < 112 ? h : 111;   // clamped rows feed only masked outputs
      const signed char* src = xt + (((size_t)n * 112 + h) * 128 + wo_base) * 64;
      g2lds16(src + lane * 16, &Xs[r * ROWB]);
      g2lds16(src + 1024 + lane * 16, &Xs[r * ROWB + 1024]);
    }
    asm volatile("s_waitcnt vmcnt(0)" ::: "memory");
    __syncthreads();

    i32x4 acc[16];
    #pragma unroll
    for (int j = 0; j < 16; ++j) acc[j] = (i32x4){0, 0, 0, 0};

    kw_body<0>(k0, aB, Xs, lrow, lkg, A0, A1, A2, acc);
    kw_body<1>(k1, aB, Xs, lrow, lkg, A0, A1, A2, acc);
    kw_body<2>(k2, aB, Xs, lrow, lkg, A0, A1, A2, acc);
    kw_body<0>(k3, aB, Xs, lrow, lkg, A0, A1, A2, acc);
    kw_body<1>(k4, aB, Xs, lrow, lkg, A0, A1, A2, acc);
    kw_body<2>(k5, aB, Xs, lrow, lkg, A0, A1, A2, acc);
    kw_body<0>(k6, aB, Xs, lrow, lkg, A0, A1, A2, acc);

    // epilogue: C/D map col=lane&15 (wo), row=(lane>>4)*4+jj (co); i32->f32 exact
    const int wo = wo_base + lrow;
    if (wo < 106) {
      const int co = coh * 64 + wid * 16 + lkg * 4;
      #pragma unroll
      for (int j = 0; j < 16; ++j) {
        const int ho = ho_base + j;
        if (ho < 106) {
          float* op = out + (((size_t)n * 128 + co) * 106 + ho) * 106 + wo;
          #pragma unroll
          for (int jj = 0; jj < 4; ++jj)
            op[(size_t)jj * 11236] = (float)acc[j][jj];
        }
      }
    }
  }
}

// ---- fallback (small ws): static grid 1568, stages straight from NCHW x
__global__ __launch_bounds__(256, 3)
void conv7f(const int* __restrict__ x,
            const signed char* __restrict__ wb, float* __restrict__ out) {
  __shared__ __align__(16) unsigned char Xs[XROWS * ROWB];

  const int tid  = threadIdx.x;
  const int lane = tid & 63;
  const int wid  = tid >> 6;
  const int lrow = lane & 15;
  const int lkg  = lane >> 4;

  const int L  = blockIdx.x;
  const int Lp = (L & 7) * 196 + (L >> 3);
  const int coh = Lp & 1;
  const int r2  = Lp >> 1;
  const int bx  = r2 % 7;
  const int t7  = r2 / 7;
  const int by  = t7 % 7;
  const int n   = t7 / 7;
  const int ho_base = by * 16;
  const int wo_base = bx * 16;

  const signed char* aB = wb + lkg * 2048 + coh * 1024 + lrow * 16;
  i32x4 A[4];
  #pragma unroll
  for (int m = 0; m < 4; ++m) A[m] = *(const i32x4*)(aB + m * 256);

  {
    const int w_a  = tid & 15,       cg_a  = tid >> 4;
    const int w_b2 = 16 + (tid & 7), cg_b2 = tid >> 3;
    const bool doB = (tid < 128) && ((tid & 7) < 6);
    const int keyA = ((w_a >> 1) & 3) << 2;
    const int keyB = ((w_b2 >> 1) & 3) << 2;
    for (int r = 0; r < XROWS; ++r) {
      int h = ho_base + r; h = h < 112 ? h : 111;
      const int* xr = x + (size_t)n * 64 * 12544 + h * 112;
      {
        int wc = wo_base + w_a; wc = wc < 112 ? wc : 111;
        uint32_t v = 0;
        #pragma unroll
        for (int j = 0; j < 4; ++j) {
          int a = xr[(cg_a * 4 + j) * 12544 + wc];
          a = a < 0 ? 0 : (a > 7 ? 7 : a);
          v |= (uint32_t)a << (8 * j);
        }
        *(uint32_t*)&Xs[r * ROWB + w_a * 64 + ((cg_a ^ keyA) << 2)] = v;
      }
      if (doB) {
        int wc = wo_base + w_b2; wc = wc < 112 ? wc : 111;
        uint32_t v = 0;
        #pragma unroll
        for (int j = 0; j < 4; ++j) {
          int a = xr[(cg_b2 * 4 + j) * 12544 + wc];
          a = a < 0 ? 0 : (a > 7 ? 7 : a);
          v |= (uint32_t)a << (8 * j);
        }
        *(uint32_t*)&Xs[r * ROWB + w_b2 * 64 + ((cg_b2 ^ keyB) << 2)] = v;
      }
    }
  }
  __syncthreads();

  i32x4 acc[4][4];
  #pragma unroll
  for (int m = 0; m < 4; ++m)
    #pragma unroll
    for (int b = 0; b < 4; ++b)
      acc[m][b] = (i32x4){0, 0, 0, 0};

  const int rowB = wid * 4;

  for (int kw = 0; kw < 7; ++kw) {
    const int w_l  = lrow + kw;
    const int bcol = w_l * 64 + ((lkg ^ ((w_l >> 1) & 3)) << 4);
    i32x4 B[8];
    #pragma unroll
    for (int b = 0; b < 4; ++b)
      B[b] = *(const i32x4*)&Xs[(rowB + b) * ROWB + bcol];
    #pragma unroll
    for (int kh = 0; kh < 7; ++kh) {
      if (kh < 6)
        B[(kh + 4) & 7] = *(const i32x4*)&Xs[(rowB + kh + 4) * ROWB + bcol];
      const signed char* apn = aB + (size_t)(kh < 6 ? (kh + 1) * 7 + kw : kw + 1) * WSLICE;
      #pragma unroll
      for (int m = 0; m < 4; ++m) {
        #pragma unroll
        for (int b = 0; b < 4; ++b)
          MFMA16(acc[m][b], A[m], B[(kh + b) & 7]);
        A[m] = *(const i32x4*)(apn + m * 256);
      }
    }
  }

  const int wo = wo_base + lrow;
  if (wo < 106) {
    #pragma unroll
    for (int m = 0; m < 4; ++m) {
      const int co = coh * 64 + m * 16 + lkg * 4;
      #pragma unroll
      for (int b = 0; b < 4; ++b) {
        const int ho = ho_base + rowB + b;
        if (ho < 106) {
          float* op = out + (((size_t)n * 128 + co) * 106 + ho) * 106 + wo;
          #pragma unroll
          for (int j = 0; j < 4; ++j)
            op[(size_t)j * 11236] = (float)acc[m][b][j];
        }
      }
    }
  }
}

extern "C" void kernel_launch(void* const* d_in, const int* in_sizes, int n_in,
                              void* d_out, int out_size, void* d_ws, size_t ws_size,
                              hipStream_t stream) {
  const int*   x  = (const int*)d_in[0];
  const float* w1 = (const float*)d_in[1];
  const float* w2 = (const float*)d_in[2];
  const float* w3 = (const float*)d_in[3];
  float* outp = (float*)d_out;
  signed char* wbp = (signed char*)d_ws;
  signed char* xtp = wbp + WB_BYTES;

  if (ws_size >= WB_BYTES + XT_BYTES) {
    prep_xw<<<dim3(2, 112, 16), dim3(256), 0, stream>>>(x, w1, w2, w3, xtp, wbp);
    conv7s<<<dim3(GRID_MAIN), dim3(256), 0, stream>>>(xtp, wbp, outp);
  } else {
    prep_w<<<dim3(1568), dim3(256), 0, stream>>>(w1, w2, w3, wbp);
    conv7f<<<dim3(1568), dim3(256), 0, stream>>>(x, wbp, outp);
  }
}